// Round 1
// baseline (1874.913 us; speedup 1.0000x reference)
//
#include <hip/hip_runtime.h>
#include <cstddef>

#define B_SZ    512
#define H_SZ    512
#define E_SZ    300
#define LC_SZ   100
#define O_SZ    2004
#define ATTN_IN 52524
#define GRU_IN  1324
#define MLP_IN  1836
#define KSPLIT  32
#define KCHUNK  1648

// ---------------------------------------------------------------------------
// Embedding gather: writes emb into xm[b][1536 : 1836]
// ---------------------------------------------------------------------------
__global__ __launch_bounds__(256) void embed_kernel(
    const int* __restrict__ input, const int* __restrict__ input_d,
    const float* __restrict__ emb_w, const float* __restrict__ emb_d_w,
    float* __restrict__ xm)
{
    int idx = blockIdx.x * 256 + threadIdx.x;           // B*E = 153600
    if (idx >= B_SZ * E_SZ) return;
    int b = idx / E_SZ, e = idx % E_SZ;
    int tok = input[b];
    float v;
    if (tok > 2003) {
        int di = tok - 2004;
        di = min(max(di, 0), LC_SZ - 1);
        int dt = input_d[b * LC_SZ + di];
        v = emb_d_w[(size_t)dt * E_SZ + e];
    } else {
        int t = min(max(tok, 0), 2103);
        v = emb_w[(size_t)t * E_SZ + e];
    }
    xm[(size_t)b * MLP_IN + 1536 + e] = v;
}

// ---------------------------------------------------------------------------
// Attention GEMM, split-K. C[b][l] = sum_k in_attn[b][k] * attn_W[l][k]
// in_attn read piecewise: [h0 | emb(from xm) | ans | annot]
// Each (mtile, split) block writes its own partial slice (deterministic).
// ---------------------------------------------------------------------------
__global__ __launch_bounds__(256) void attn_gemm(
    const float* __restrict__ h0, const float* __restrict__ xm,
    const float* __restrict__ ans, const float* __restrict__ annot,
    const float* __restrict__ attn_W, float* __restrict__ partial)
{
    __shared__ __align__(16) float As[16][68];
    __shared__ __align__(16) float Ws[16][132];
    const int tid   = threadIdx.x;
    const int bm    = blockIdx.x * 64;
    const int split = blockIdx.y;
    const int kbase = split * KCHUNK;
    const int kend  = min(kbase + KCHUNK, ATTN_IN);
    const int tm = (tid & 15) * 4;
    const int tn = (tid >> 4) * 8;
    float acc[4][8] = {};

    for (int k0 = kbase; k0 < kend; k0 += 16) {
#pragma unroll
        for (int i = 0; i < 4; ++i) {
            int e  = tid + i * 256;
            int ki = e & 15, mi = e >> 4;
            int gk = k0 + ki;
            int b  = bm + mi;
            float v = 0.0f;
            if (gk < kend) {
                if (gk < 512)        v = h0[b * 512 + gk];
                else if (gk < 812)   v = xm[(size_t)b * MLP_IN + 1536 + (gk - 512)];
                else if (gk < 1324)  v = ans[b * 512 + (gk - 812)];
                else                 v = annot[(size_t)b * 51200 + (gk - 1324)];
            }
            As[ki][mi] = v;
        }
#pragma unroll
        for (int i = 0; i < 8; ++i) {
            int e  = tid + i * 256;
            int ki = e & 15, ni = e >> 4;
            int gk = k0 + ki;
            float v = 0.0f;
            if (ni < LC_SZ && gk < kend) v = attn_W[(size_t)ni * ATTN_IN + gk];
            Ws[ki][ni] = v;
        }
        __syncthreads();
#pragma unroll
        for (int kk = 0; kk < 16; ++kk) {
            float4 a  = *reinterpret_cast<const float4*>(&As[kk][tm]);
            float4 w0 = *reinterpret_cast<const float4*>(&Ws[kk][tn]);
            float4 w1 = *reinterpret_cast<const float4*>(&Ws[kk][tn + 4]);
            acc[0][0] += a.x * w0.x; acc[0][1] += a.x * w0.y; acc[0][2] += a.x * w0.z; acc[0][3] += a.x * w0.w;
            acc[0][4] += a.x * w1.x; acc[0][5] += a.x * w1.y; acc[0][6] += a.x * w1.z; acc[0][7] += a.x * w1.w;
            acc[1][0] += a.y * w0.x; acc[1][1] += a.y * w0.y; acc[1][2] += a.y * w0.z; acc[1][3] += a.y * w0.w;
            acc[1][4] += a.y * w1.x; acc[1][5] += a.y * w1.y; acc[1][6] += a.y * w1.z; acc[1][7] += a.y * w1.w;
            acc[2][0] += a.z * w0.x; acc[2][1] += a.z * w0.y; acc[2][2] += a.z * w0.z; acc[2][3] += a.z * w0.w;
            acc[2][4] += a.z * w1.x; acc[2][5] += a.z * w1.y; acc[2][6] += a.z * w1.z; acc[2][7] += a.z * w1.w;
            acc[3][0] += a.w * w0.x; acc[3][1] += a.w * w0.y; acc[3][2] += a.w * w0.z; acc[3][3] += a.w * w0.w;
            acc[3][4] += a.w * w1.x; acc[3][5] += a.w * w1.y; acc[3][6] += a.w * w1.z; acc[3][7] += a.w * w1.w;
        }
        __syncthreads();
    }
#pragma unroll
    for (int i = 0; i < 4; ++i) {
        int b = bm + tm + i;
#pragma unroll
        for (int j = 0; j < 8; ++j) {
            int l = tn + j;
            if (l < LC_SZ)
                partial[(size_t)split * (B_SZ * LC_SZ) + b * LC_SZ + l] = acc[i][j];
        }
    }
}

// ---------------------------------------------------------------------------
// Per-b: reduce split-K partials + bias -> tanh -> softmax(100) -> attn_w;
// c_t[h] = sum_l w[l]*annot[b][l][h]; also fills xm c_t and ans regions.
// ---------------------------------------------------------------------------
__global__ __launch_bounds__(256) void attn_softmax_ct(
    const float* __restrict__ partial, const float* __restrict__ attn_b,
    const float* __restrict__ annot, const float* __restrict__ ans,
    float* __restrict__ attn_w_out, float* __restrict__ xm)
{
    int b = blockIdx.x, tid = threadIdx.x;
    __shared__ float sw[LC_SZ];
    __shared__ float red[256];

    float v = -1e30f;
    if (tid < LC_SZ) {
        float s = attn_b[tid];
        for (int sp = 0; sp < KSPLIT; ++sp)
            s += partial[(size_t)sp * (B_SZ * LC_SZ) + b * LC_SZ + tid];
        v = tanhf(s);
        sw[tid] = v;
    }
    red[tid] = v; __syncthreads();
    for (int s = 128; s > 0; s >>= 1) { if (tid < s) red[tid] = fmaxf(red[tid], red[tid + s]); __syncthreads(); }
    float mx = red[0]; __syncthreads();

    float e = 0.0f;
    if (tid < LC_SZ) e = expf(sw[tid] - mx);
    red[tid] = e; __syncthreads();
    for (int s = 128; s > 0; s >>= 1) { if (tid < s) red[tid] += red[tid + s]; __syncthreads(); }
    float denom = red[0]; __syncthreads();

    if (tid < LC_SZ) {
        float w = e / denom;
        sw[tid] = w;
        attn_w_out[b * LC_SZ + tid] = w;
    }
    __syncthreads();

    for (int h = tid; h < H_SZ; h += 256) {
        float acc = 0.0f;
        for (int l = 0; l < LC_SZ; ++l)
            acc += sw[l] * annot[(size_t)b * (LC_SZ * H_SZ) + l * H_SZ + h];
        xm[(size_t)b * MLP_IN + 512 + h]  = acc;              // c_t
        xm[(size_t)b * MLP_IN + 1024 + h] = ans[b * 512 + h]; // ans
    }
}

// ---------------------------------------------------------------------------
// Generic f32 GEMM: C[m][n] = act(bias[n] + sum_k A[m*lda+k]*W[n*K+k])
// M fixed at 512 (grid.x = 8). 64x64 tile, 4x4 microtile. act: 0=none,1=tanh
// ---------------------------------------------------------------------------
__global__ __launch_bounds__(256) void gemm_bt(
    const float* __restrict__ A, int lda,
    const float* __restrict__ W, const float* __restrict__ bias,
    float* __restrict__ C, int ldc, int N, int K, int act)
{
    __shared__ __align__(16) float As[16][68];
    __shared__ __align__(16) float Ws[16][68];
    const int tid = threadIdx.x;
    const int bm = blockIdx.x * 64;
    const int bn = blockIdx.y * 64;
    const int tm = (tid & 15) * 4;
    const int tn = (tid >> 4) * 4;
    float acc[4][4] = {};

    for (int k0 = 0; k0 < K; k0 += 16) {
#pragma unroll
        for (int i = 0; i < 4; ++i) {
            int e  = tid + i * 256;
            int ki = e & 15, mi = e >> 4;
            int gk = k0 + ki;
            As[ki][mi] = (gk < K) ? A[(size_t)(bm + mi) * lda + gk] : 0.0f;
        }
#pragma unroll
        for (int i = 0; i < 4; ++i) {
            int e  = tid + i * 256;
            int ki = e & 15, ni = e >> 4;
            int gk = k0 + ki, gn = bn + ni;
            Ws[ki][ni] = (gk < K && gn < N) ? W[(size_t)gn * K + gk] : 0.0f;
        }
        __syncthreads();
#pragma unroll
        for (int kk = 0; kk < 16; ++kk) {
            float4 a = *reinterpret_cast<const float4*>(&As[kk][tm]);
            float4 w = *reinterpret_cast<const float4*>(&Ws[kk][tn]);
            acc[0][0] += a.x * w.x; acc[0][1] += a.x * w.y; acc[0][2] += a.x * w.z; acc[0][3] += a.x * w.w;
            acc[1][0] += a.y * w.x; acc[1][1] += a.y * w.y; acc[1][2] += a.y * w.z; acc[1][3] += a.y * w.w;
            acc[2][0] += a.z * w.x; acc[2][1] += a.z * w.y; acc[2][2] += a.z * w.z; acc[2][3] += a.z * w.w;
            acc[3][0] += a.w * w.x; acc[3][1] += a.w * w.y; acc[3][2] += a.w * w.z; acc[3][3] += a.w * w.w;
        }
        __syncthreads();
    }
#pragma unroll
    for (int i = 0; i < 4; ++i) {
        int m = bm + tm + i;
#pragma unroll
        for (int j = 0; j < 4; ++j) {
            int n = bn + tn + j;
            if (n < N) {
                float v = acc[i][j] + bias[n];
                if (act == 1) v = tanhf(v);
                C[(size_t)m * ldc + n] = v;
            }
        }
    }
}

// ---------------------------------------------------------------------------
// GRU elementwise; writes h_new into xm[b][0:512] and into d_out slots 0 & 1
// ---------------------------------------------------------------------------
__global__ __launch_bounds__(256) void gru_kernel(
    const float* __restrict__ gi, const float* __restrict__ gh,
    const float* __restrict__ h0, float* __restrict__ xm,
    float* __restrict__ out01)
{
    int idx = blockIdx.x * 256 + threadIdx.x;   // B*H
    int b = idx >> 9, h = idx & 511;
    float ir  = gi[(size_t)b * 1536 + h];
    float iz  = gi[(size_t)b * 1536 + 512 + h];
    float inn = gi[(size_t)b * 1536 + 1024 + h];
    float hr  = gh[(size_t)b * 1536 + h];
    float hz  = gh[(size_t)b * 1536 + 512 + h];
    float hn  = gh[(size_t)b * 1536 + 1024 + h];
    float r = 1.0f / (1.0f + expf(-(ir + hr)));
    float z = 1.0f / (1.0f + expf(-(iz + hz)));
    float n = tanhf(inn + r * hn);
    float hp = h0[idx];
    float hv = (1.0f - z) * n + z * hp;
    xm[(size_t)b * MLP_IN + h] = hv;
    out01[idx] = hv;
    out01[B_SZ * H_SZ + idx] = hv;
}

// ---------------------------------------------------------------------------
// z_t[b] = sigmoid(dot(z2[b], W3) + b3): one wave per b
// ---------------------------------------------------------------------------
__global__ __launch_bounds__(64) void zt_kernel(
    const float* __restrict__ z2, const float* __restrict__ W3,
    const float* __restrict__ b3, float* __restrict__ z_t)
{
    int b = blockIdx.x, lane = threadIdx.x;
    float acc = 0.0f;
    for (int k = lane; k < H_SZ; k += 64) acc += z2[(size_t)b * H_SZ + k] * W3[k];
    for (int off = 32; off > 0; off >>= 1) acc += __shfl_down(acc, off, 64);
    if (lane == 0) z_t[b] = 1.0f / (1.0f + expf(-(acc + b3[0])));
}

// ---------------------------------------------------------------------------
// Final: softmax(2004) per b, p_t = log([o*z, attn_w*(1-z)] + 1e-20)
// ---------------------------------------------------------------------------
__global__ __launch_bounds__(256) void out_softmax(
    const float* __restrict__ lo, const float* __restrict__ attn_w,
    const float* __restrict__ z_t, float* __restrict__ pt)
{
    int b = blockIdx.x, tid = threadIdx.x;
    __shared__ float red[256];
    float mx = -1e30f;
    for (int o = tid; o < O_SZ; o += 256) mx = fmaxf(mx, lo[(size_t)b * O_SZ + o]);
    red[tid] = mx; __syncthreads();
    for (int s = 128; s > 0; s >>= 1) { if (tid < s) red[tid] = fmaxf(red[tid], red[tid + s]); __syncthreads(); }
    mx = red[0]; __syncthreads();
    float sm = 0.0f;
    for (int o = tid; o < O_SZ; o += 256) sm += expf(lo[(size_t)b * O_SZ + o] - mx);
    red[tid] = sm; __syncthreads();
    for (int s = 128; s > 0; s >>= 1) { if (tid < s) red[tid] += red[tid + s]; __syncthreads(); }
    float denom = red[0];
    float zt = z_t[b];
    float inv = 1.0f / denom;
    for (int o = tid; o < O_SZ; o += 256) {
        float p = expf(lo[(size_t)b * O_SZ + o] - mx) * inv;
        pt[(size_t)b * 2104 + o] = logf(p * zt + 1e-20f);
    }
    for (int l = tid; l < LC_SZ; l += 256)
        pt[(size_t)b * 2104 + O_SZ + l] = logf(attn_w[b * LC_SZ + l] * (1.0f - zt) + 1e-20f);
}

// ---------------------------------------------------------------------------
extern "C" void kernel_launch(void* const* d_in, const int* in_sizes, int n_in,
                              void* d_out, int out_size, void* d_ws, size_t ws_size,
                              hipStream_t stream)
{
    const int*   input   = (const int*)d_in[0];
    const int*   input_d = (const int*)d_in[1];
    const float* hidden  = (const float*)d_in[2];
    const float* annot   = (const float*)d_in[3];
    const float* ans     = (const float*)d_in[4];
    const float* emb_w   = (const float*)d_in[5];
    const float* emb_d_w = (const float*)d_in[6];
    const float* attn_W  = (const float*)d_in[7];
    const float* attn_b  = (const float*)d_in[8];
    const float* W_ih    = (const float*)d_in[9];
    const float* W_hh    = (const float*)d_in[10];
    const float* b_ih    = (const float*)d_in[11];
    const float* b_hh    = (const float*)d_in[12];
    const float* mlp_W   = (const float*)d_in[13];
    const float* mlp_b   = (const float*)d_in[14];
    const float* out_W   = (const float*)d_in[15];
    const float* out_b   = (const float*)d_in[16];
    const float* zt_W1   = (const float*)d_in[17];
    const float* zt_b1   = (const float*)d_in[18];
    const float* zt_W2   = (const float*)d_in[19];
    const float* zt_b2   = (const float*)d_in[20];
    const float* zt_W3   = (const float*)d_in[21];
    const float* zt_b3   = (const float*)d_in[22];

    float* ws      = (float*)d_ws;
    float* xm      = ws;                       // 512*1836   = 940032
    float* partial = ws + 940032;              // 32*51200   = 1638400
    float* attn_w  = ws + 2578432;             // 51200
    float* gi      = ws + 2629632;             // 786432
    float* gh      = ws + 3416064;             // 786432
    float* e_t     = ws + 4202496;             // 262144
    float* lo      = ws + 4464640;             // 1026048
    float* z1      = ws + 5490688;             // 524288
    float* z2      = ws + 6014976;             // 262144
    float* z_t     = ws + 6277120;             // 512

    float* out = (float*)d_out;

    embed_kernel<<<600, 256, 0, stream>>>(input, input_d, emb_w, emb_d_w, xm);
    attn_gemm<<<dim3(8, KSPLIT), 256, 0, stream>>>(hidden, xm, ans, annot, attn_W, partial);
    attn_softmax_ct<<<512, 256, 0, stream>>>(partial, attn_b, annot, ans, attn_w, xm);
    gemm_bt<<<dim3(8, 24), 256, 0, stream>>>(xm + 512, MLP_IN, W_ih, b_ih, gi, 1536, 1536, GRU_IN, 0);
    gemm_bt<<<dim3(8, 24), 256, 0, stream>>>(hidden, 512, W_hh, b_hh, gh, 1536, 1536, 512, 0);
    gru_kernel<<<1024, 256, 0, stream>>>(gi, gh, hidden, xm, out);
    gemm_bt<<<dim3(8, 8),  256, 0, stream>>>(xm, MLP_IN, mlp_W, mlp_b, e_t, 512, 512, MLP_IN, 0);
    gemm_bt<<<dim3(8, 32), 256, 0, stream>>>(e_t, 512, out_W, out_b, lo, O_SZ, O_SZ, 512, 0);
    gemm_bt<<<dim3(8, 16), 256, 0, stream>>>(xm, MLP_IN, zt_W1, zt_b1, z1, 1024, 1024, MLP_IN, 1);
    gemm_bt<<<dim3(8, 8),  256, 0, stream>>>(z1, 1024, zt_W2, zt_b2, z2, 512, 512, 1024, 1);
    zt_kernel<<<512, 64, 0, stream>>>(z2, zt_W3, zt_b3, z_t);
    out_softmax<<<512, 256, 0, stream>>>(lo, attn_w, z_t, out + 524288);
}

// Round 2
// 462.999 us; speedup vs baseline: 4.0495x; 4.0495x over previous
//
#include <hip/hip_runtime.h>
#include <cstddef>

typedef __attribute__((ext_vector_type(8))) short short8;
typedef __attribute__((ext_vector_type(4))) float f32x4;

#define B_SZ   512
#define H_SZ   512
#define E_SZ   300
#define LC_SZ  100
#define O_SZ   2004
#define AK     52528   // padded attention K (real 52524)
#define XK     1840    // xm_bf row stride (real 1836)
#define GIK    1328    // padded GRU-input K (real 1324)
#define KSPLIT 64
#define KCHUNK 832

__device__ __forceinline__ unsigned short f2bf(float f) {
    union { float f; unsigned u; } x; x.f = f;
    unsigned r = x.u + 0x7FFFu + ((x.u >> 16) & 1u);
    return (unsigned short)(r >> 16);
}
__device__ __forceinline__ float bf2f(unsigned short h) {
    union { unsigned u; float f; } x; x.u = ((unsigned)h) << 16;
    return x.f;
}

// ---------------------------------------------------------------------------
// Convert all weight matrices f32 -> bf16 with rows padded to mult-of-8, pads=0
// segs: attn_W, W_ih, W_hh, mlp_W, out_W, zt_W1, zt_W2
// ---------------------------------------------------------------------------
__global__ __launch_bounds__(256) void cvt_weights(
    const float* s0, const float* s1, const float* s2, const float* s3,
    const float* s4, const float* s5, const float* s6,
    unsigned short* d0, unsigned short* d1, unsigned short* d2, unsigned short* d3,
    unsigned short* d4, unsigned short* d5, unsigned short* d6)
{
    const int cum[7]   = {2565, 3561, 3945, 4405, 4906, 5826, 6082};
    const int Ks[7]    = {52524, 1324, 512, 1836, 512, 1836, 1024};
    const int ldd[7]   = {52528, 1328, 512, 1840, 512, 1840, 1024};
    const int elems[7] = {5252800, 2039808, 786432, 942080, 1026048, 1884160, 524288};
    int blk = blockIdx.x;
    int seg = 0;
    while (seg < 6 && blk >= cum[seg]) seg++;
    int base = (seg == 0) ? 0 : cum[seg - 1];
    const float* src = seg==0?s0:seg==1?s1:seg==2?s2:seg==3?s3:seg==4?s4:seg==5?s5:s6;
    unsigned short* dst = seg==0?d0:seg==1?d1:seg==2?d2:seg==3?d3:seg==4?d4:seg==5?d5:d6;
    int K = Ks[seg], L = ldd[seg];
    int idx = (blk - base) * 2048 + threadIdx.x * 8;
    if (idx >= elems[seg]) return;
    int row = idx / L;
    int col = idx - row * L;
    unsigned short tmp[8];
    if (col + 8 <= K) {
        const float* sp = src + (size_t)row * K + col;
        float4 a = *(const float4*)sp;
        float4 b = *(const float4*)(sp + 4);
        tmp[0]=f2bf(a.x); tmp[1]=f2bf(a.y); tmp[2]=f2bf(a.z); tmp[3]=f2bf(a.w);
        tmp[4]=f2bf(b.x); tmp[5]=f2bf(b.y); tmp[6]=f2bf(b.z); tmp[7]=f2bf(b.w);
    } else {
        for (int j = 0; j < 8; ++j) {
            int c = col + j;
            tmp[j] = (c < K) ? f2bf(src[(size_t)row * K + c]) : (unsigned short)0;
        }
    }
    *(int4*)(dst + (size_t)row * L + col) = *(int4*)tmp;
}

// ---------------------------------------------------------------------------
// Embedding: bf16 emb into Abf[b][512+e] and xm_bf[b][1536+e]; zero xm pad
// ---------------------------------------------------------------------------
__global__ __launch_bounds__(256) void embed_kernel(
    const int* __restrict__ input, const int* __restrict__ input_d,
    const float* __restrict__ emb_w, const float* __restrict__ emb_d_w,
    unsigned short* __restrict__ Abf, unsigned short* __restrict__ xm_bf)
{
    int idx = blockIdx.x * 256 + threadIdx.x;   // 512*304
    if (idx >= B_SZ * 304) return;
    int b = idx / 304, e = idx % 304;
    if (e >= E_SZ) { xm_bf[(size_t)b * XK + 1536 + e] = 0; return; }
    int tok = input[b];
    float v;
    if (tok > 2003) {
        int di = tok - 2004;
        di = min(max(di, 0), LC_SZ - 1);
        int dt = input_d[b * LC_SZ + di];
        v = emb_d_w[(size_t)dt * E_SZ + e];
    } else {
        int t = min(max(tok, 0), 2103);
        v = emb_w[(size_t)t * E_SZ + e];
    }
    unsigned short h = f2bf(v);
    Abf[(size_t)b * AK + 512 + e]   = h;
    xm_bf[(size_t)b * XK + 1536 + e] = h;
}

// ---------------------------------------------------------------------------
// Build bf16 in_attn matrix: [h0 | (emb by embed_kernel) | ans | annot | pad]
// also copies ans (bf16) into xm_bf[b][1024..1535]
// ---------------------------------------------------------------------------
__global__ __launch_bounds__(256) void build_abf(
    const float* __restrict__ h0, const float* __restrict__ ans,
    const float* __restrict__ annot,
    unsigned short* __restrict__ Abf, unsigned short* __restrict__ xm_bf)
{
    int idx = blockIdx.x * 256 + threadIdx.x;   // 512 * 13132 float4-groups
    if (idx >= B_SZ * 13132) return;
    int b = idx / 13132, k4 = idx % 13132;
    if (k4 >= 128 && k4 < 203) return;          // emb region handled elsewhere
    unsigned short o[4];
    if (k4 == 13131) {
        o[0] = o[1] = o[2] = o[3] = 0;
    } else {
        const float* sp;
        if (k4 < 128)       sp = h0    + (size_t)b * 512   + k4 * 4;
        else if (k4 < 331)  sp = ans   + (size_t)b * 512   + (k4 - 203) * 4;
        else                sp = annot + (size_t)b * 51200 + (size_t)(k4 - 331) * 4;
        float4 f = *(const float4*)sp;
        o[0] = f2bf(f.x); o[1] = f2bf(f.y); o[2] = f2bf(f.z); o[3] = f2bf(f.w);
        if (k4 >= 203 && k4 < 331)
            *(unsigned long long*)(xm_bf + (size_t)b * XK + 1024 + (k4 - 203) * 4) =
                *(unsigned long long*)o;
    }
    *(unsigned long long*)(Abf + (size_t)b * AK + k4 * 4) = *(unsigned long long*)o;
}

// ---------------------------------------------------------------------------
// Generic bf16 MFMA GEMM: C[m][n] = act(bias[n] + sum_k A[m][k]*W[n][k])
// BM=BN=64, BK=64, 256 thr (2x2 waves, each 32x32 via 2x2 mfma 16x16x32)
// ---------------------------------------------------------------------------
__global__ __launch_bounds__(256) void gemm_bf(
    const unsigned short* __restrict__ A, long lda,
    const unsigned short* __restrict__ Wb, long ldw,
    const float* __restrict__ bias,
    float* __restrict__ Cf, unsigned short* __restrict__ Cb,
    int ldc, int N, int Kpad, int act)
{
    __shared__ unsigned short As[64][72];
    __shared__ unsigned short Bs[64][72];
    const int t = threadIdx.x;
    const int lane = t & 63, w = t >> 6;
    const int wm = w >> 1, wn = w & 1;
    const int bm = blockIdx.x * 64, bn = blockIdx.y * 64;
    const int srow = t >> 2, scol = (t & 3) * 16;
    f32x4 acc[2][2] = {};

    for (int k0 = 0; k0 < Kpad; k0 += 64) {
#pragma unroll
        for (int i = 0; i < 2; ++i) {
            int gk = k0 + scol + i * 8;
            int4 v = {0, 0, 0, 0};
            if (gk < Kpad) v = *(const int4*)(A + (size_t)(bm + srow) * lda + gk);
            *(int4*)&As[srow][scol + i * 8] = v;
        }
        int gn = bn + srow;
#pragma unroll
        for (int i = 0; i < 2; ++i) {
            int gk = k0 + scol + i * 8;
            int4 v = {0, 0, 0, 0};
            if (gk < Kpad && gn < N) v = *(const int4*)(Wb + (size_t)gn * ldw + gk);
            *(int4*)&Bs[srow][scol + i * 8] = v;
        }
        __syncthreads();
#pragma unroll
        for (int kk = 0; kk < 2; ++kk) {
            short8 a0 = *(const short8*)&As[wm * 32 +      (lane & 15)][kk * 32 + (lane >> 4) * 8];
            short8 a1 = *(const short8*)&As[wm * 32 + 16 + (lane & 15)][kk * 32 + (lane >> 4) * 8];
            short8 b0 = *(const short8*)&Bs[wn * 32 +      (lane & 15)][kk * 32 + (lane >> 4) * 8];
            short8 b1 = *(const short8*)&Bs[wn * 32 + 16 + (lane & 15)][kk * 32 + (lane >> 4) * 8];
            acc[0][0] = __builtin_amdgcn_mfma_f32_16x16x32_bf16(a0, b0, acc[0][0], 0, 0, 0);
            acc[0][1] = __builtin_amdgcn_mfma_f32_16x16x32_bf16(a0, b1, acc[0][1], 0, 0, 0);
            acc[1][0] = __builtin_amdgcn_mfma_f32_16x16x32_bf16(a1, b0, acc[1][0], 0, 0, 0);
            acc[1][1] = __builtin_amdgcn_mfma_f32_16x16x32_bf16(a1, b1, acc[1][1], 0, 0, 0);
        }
        __syncthreads();
    }
#pragma unroll
    for (int tt = 0; tt < 2; ++tt) {
        int n = bn + wn * 32 + tt * 16 + (lane & 15);
        if (n >= N) continue;
        float bv = bias[n];
#pragma unroll
        for (int s = 0; s < 2; ++s) {
#pragma unroll
            for (int r = 0; r < 4; ++r) {
                int m = bm + wm * 32 + s * 16 + (lane >> 4) * 4 + r;
                float v = acc[s][tt][r] + bv;
                if (act == 1) v = tanhf(v);
                if (Cf) Cf[(size_t)m * ldc + n] = v;
                if (Cb) Cb[(size_t)m * ldc + n] = f2bf(v);
            }
        }
    }
}

// ---------------------------------------------------------------------------
// Attention GEMM: split-K over Abf(512xAK) @ attn_W_bf(100xAK)^T -> partial
// ---------------------------------------------------------------------------
__global__ __launch_bounds__(256) void attn_gemm_bf(
    const unsigned short* __restrict__ A, const unsigned short* __restrict__ Wb,
    float* __restrict__ partial)
{
    __shared__ unsigned short As[64][72];
    __shared__ unsigned short Bs[64][72];
    const int t = threadIdx.x;
    const int lane = t & 63, w = t >> 6;
    const int wm = w >> 1, wn = w & 1;
    const int bm = blockIdx.x * 64, bn = blockIdx.y * 64;
    const int z  = blockIdx.z;
    const int kbase = z * KCHUNK;
    const int kend  = min(kbase + KCHUNK, AK);
    const int srow = t >> 2, scol = (t & 3) * 16;
    f32x4 acc[2][2] = {};

    for (int k0 = kbase; k0 < kend; k0 += 64) {
#pragma unroll
        for (int i = 0; i < 2; ++i) {
            int gk = k0 + scol + i * 8;
            int4 v = {0, 0, 0, 0};
            if (gk < kend) v = *(const int4*)(A + (size_t)(bm + srow) * AK + gk);
            *(int4*)&As[srow][scol + i * 8] = v;
        }
        int gn = bn + srow;
#pragma unroll
        for (int i = 0; i < 2; ++i) {
            int gk = k0 + scol + i * 8;
            int4 v = {0, 0, 0, 0};
            if (gk < kend && gn < LC_SZ) v = *(const int4*)(Wb + (size_t)gn * AK + gk);
            *(int4*)&Bs[srow][scol + i * 8] = v;
        }
        __syncthreads();
#pragma unroll
        for (int kk = 0; kk < 2; ++kk) {
            short8 a0 = *(const short8*)&As[wm * 32 +      (lane & 15)][kk * 32 + (lane >> 4) * 8];
            short8 a1 = *(const short8*)&As[wm * 32 + 16 + (lane & 15)][kk * 32 + (lane >> 4) * 8];
            short8 b0 = *(const short8*)&Bs[wn * 32 +      (lane & 15)][kk * 32 + (lane >> 4) * 8];
            short8 b1 = *(const short8*)&Bs[wn * 32 + 16 + (lane & 15)][kk * 32 + (lane >> 4) * 8];
            acc[0][0] = __builtin_amdgcn_mfma_f32_16x16x32_bf16(a0, b0, acc[0][0], 0, 0, 0);
            acc[0][1] = __builtin_amdgcn_mfma_f32_16x16x32_bf16(a0, b1, acc[0][1], 0, 0, 0);
            acc[1][0] = __builtin_amdgcn_mfma_f32_16x16x32_bf16(a1, b0, acc[1][0], 0, 0, 0);
            acc[1][1] = __builtin_amdgcn_mfma_f32_16x16x32_bf16(a1, b1, acc[1][1], 0, 0, 0);
        }
        __syncthreads();
    }
#pragma unroll
    for (int tt = 0; tt < 2; ++tt) {
        int n = bn + wn * 32 + tt * 16 + (lane & 15);
        if (n >= LC_SZ) continue;
#pragma unroll
        for (int s = 0; s < 2; ++s) {
#pragma unroll
            for (int r = 0; r < 4; ++r) {
                int m = bm + wm * 32 + s * 16 + (lane >> 4) * 4 + r;
                partial[((size_t)z * B_SZ + m) * LC_SZ + n] = acc[s][tt][r];
            }
        }
    }
}

// ---------------------------------------------------------------------------
// Reduce partials + tanh + softmax(100); c_t from bf16 annot in Abf
// ---------------------------------------------------------------------------
__global__ __launch_bounds__(256) void attn_softmax_ct(
    const float* __restrict__ partial, const float* __restrict__ attn_b,
    const unsigned short* __restrict__ Abf,
    float* __restrict__ attn_w_out, unsigned short* __restrict__ xm_bf)
{
    int b = blockIdx.x, tid = threadIdx.x;
    __shared__ float sw[LC_SZ];
    __shared__ float red[256];

    float v = -1e30f;
    float e = 0.0f;
    if (tid < LC_SZ) {
        float s = attn_b[tid];
        for (int sp = 0; sp < KSPLIT; ++sp)
            s += partial[((size_t)sp * B_SZ + b) * LC_SZ + tid];
        v = tanhf(s);
        sw[tid] = v;
    }
    red[tid] = v; __syncthreads();
    for (int s = 128; s > 0; s >>= 1) { if (tid < s) red[tid] = fmaxf(red[tid], red[tid + s]); __syncthreads(); }
    float mx = red[0]; __syncthreads();

    if (tid < LC_SZ) e = expf(sw[tid] - mx);
    red[tid] = e; __syncthreads();
    for (int s = 128; s > 0; s >>= 1) { if (tid < s) red[tid] += red[tid + s]; __syncthreads(); }
    float denom = red[0]; __syncthreads();

    if (tid < LC_SZ) {
        float wv = e / denom;
        sw[tid] = wv;
        attn_w_out[b * LC_SZ + tid] = wv;
    }
    __syncthreads();

    const unsigned short* ab = Abf + (size_t)b * AK + 1324;
    for (int h = tid; h < H_SZ; h += 256) {
        float acc = 0.0f;
        for (int l = 0; l < LC_SZ; ++l)
            acc += sw[l] * bf2f(ab[l * 512 + h]);
        xm_bf[(size_t)b * XK + 512 + h] = f2bf(acc);
    }
}

// ---------------------------------------------------------------------------
// GRU elementwise; h_new -> out slots 0/1 (f32) and xm_bf[b][0:512] (bf16)
// ---------------------------------------------------------------------------
__global__ __launch_bounds__(256) void gru_kernel(
    const float* __restrict__ gi, const float* __restrict__ gh,
    const float* __restrict__ h0, unsigned short* __restrict__ xm_bf,
    float* __restrict__ out01)
{
    int idx = blockIdx.x * 256 + threadIdx.x;   // B*H
    int b = idx >> 9, h = idx & 511;
    float ir  = gi[(size_t)b * 1536 + h];
    float iz  = gi[(size_t)b * 1536 + 512 + h];
    float inn = gi[(size_t)b * 1536 + 1024 + h];
    float hr  = gh[(size_t)b * 1536 + h];
    float hz  = gh[(size_t)b * 1536 + 512 + h];
    float hn  = gh[(size_t)b * 1536 + 1024 + h];
    float r = 1.0f / (1.0f + expf(-(ir + hr)));
    float z = 1.0f / (1.0f + expf(-(iz + hz)));
    float n = tanhf(inn + r * hn);
    float hp = h0[idx];
    float hv = (1.0f - z) * n + z * hp;
    xm_bf[(size_t)b * XK + h] = f2bf(hv);
    out01[idx] = hv;
    out01[B_SZ * H_SZ + idx] = hv;
}

// ---------------------------------------------------------------------------
__global__ __launch_bounds__(64) void zt_kernel(
    const float* __restrict__ z2, const float* __restrict__ W3,
    const float* __restrict__ b3, float* __restrict__ z_t)
{
    int b = blockIdx.x, lane = threadIdx.x;
    float acc = 0.0f;
    for (int k = lane; k < H_SZ; k += 64) acc += z2[(size_t)b * H_SZ + k] * W3[k];
    for (int off = 32; off > 0; off >>= 1) acc += __shfl_down(acc, off, 64);
    if (lane == 0) z_t[b] = 1.0f / (1.0f + expf(-(acc + b3[0])));
}

// ---------------------------------------------------------------------------
__global__ __launch_bounds__(256) void out_softmax(
    const float* __restrict__ lo, const float* __restrict__ attn_w,
    const float* __restrict__ z_t, float* __restrict__ pt)
{
    int b = blockIdx.x, tid = threadIdx.x;
    __shared__ float red[256];
    float mx = -1e30f;
    for (int o = tid; o < O_SZ; o += 256) mx = fmaxf(mx, lo[(size_t)b * O_SZ + o]);
    red[tid] = mx; __syncthreads();
    for (int s = 128; s > 0; s >>= 1) { if (tid < s) red[tid] = fmaxf(red[tid], red[tid + s]); __syncthreads(); }
    mx = red[0]; __syncthreads();
    float sm = 0.0f;
    for (int o = tid; o < O_SZ; o += 256) sm += expf(lo[(size_t)b * O_SZ + o] - mx);
    red[tid] = sm; __syncthreads();
    for (int s = 128; s > 0; s >>= 1) { if (tid < s) red[tid] += red[tid + s]; __syncthreads(); }
    float denom = red[0];
    float zt = z_t[b];
    float inv = 1.0f / denom;
    for (int o = tid; o < O_SZ; o += 256) {
        float p = expf(lo[(size_t)b * O_SZ + o] - mx) * inv;
        pt[(size_t)b * 2104 + o] = logf(p * zt + 1e-20f);
    }
    for (int l = tid; l < LC_SZ; l += 256)
        pt[(size_t)b * 2104 + O_SZ + l] = logf(attn_w[b * LC_SZ + l] * (1.0f - zt) + 1e-20f);
}

// ---------------------------------------------------------------------------
extern "C" void kernel_launch(void* const* d_in, const int* in_sizes, int n_in,
                              void* d_out, int out_size, void* d_ws, size_t ws_size,
                              hipStream_t stream)
{
    const int*   input   = (const int*)d_in[0];
    const int*   input_d = (const int*)d_in[1];
    const float* hidden  = (const float*)d_in[2];
    const float* annot   = (const float*)d_in[3];
    const float* ans     = (const float*)d_in[4];
    const float* emb_w   = (const float*)d_in[5];
    const float* emb_d_w = (const float*)d_in[6];
    const float* attn_W  = (const float*)d_in[7];
    const float* attn_b  = (const float*)d_in[8];
    const float* W_ih    = (const float*)d_in[9];
    const float* W_hh    = (const float*)d_in[10];
    const float* b_ih    = (const float*)d_in[11];
    const float* b_hh    = (const float*)d_in[12];
    const float* mlp_W   = (const float*)d_in[13];
    const float* mlp_b   = (const float*)d_in[14];
    const float* out_W   = (const float*)d_in[15];
    const float* out_b   = (const float*)d_in[16];
    const float* zt_W1   = (const float*)d_in[17];
    const float* zt_b1   = (const float*)d_in[18];
    const float* zt_W2   = (const float*)d_in[19];
    const float* zt_b2   = (const float*)d_in[20];
    const float* zt_W3   = (const float*)d_in[21];
    const float* zt_b3   = (const float*)d_in[22];

    char* p = (char*)d_ws;
    unsigned short* Abf      = (unsigned short*)p; p += (size_t)512 * AK * 2;       // 53,788,672
    unsigned short* attnW_bf = (unsigned short*)p; p += (size_t)100 * AK * 2;       // 10,505,600
    unsigned short* Wih_bf   = (unsigned short*)p; p += (size_t)1536 * GIK * 2;     //  4,079,616
    unsigned short* Whh_bf   = (unsigned short*)p; p += (size_t)1536 * 512 * 2;     //  1,572,864
    unsigned short* mlpW_bf  = (unsigned short*)p; p += (size_t)512 * XK * 2;       //  1,884,160
    unsigned short* outW_bf  = (unsigned short*)p; p += (size_t)2004 * 512 * 2;     //  2,052,096
    unsigned short* ztW1_bf  = (unsigned short*)p; p += (size_t)1024 * XK * 2;      //  3,768,320
    unsigned short* ztW2_bf  = (unsigned short*)p; p += (size_t)512 * 1024 * 2;     //  1,048,576
    unsigned short* xm_bf    = (unsigned short*)p; p += (size_t)512 * XK * 2;       //  1,884,160
    unsigned short* et_bf    = (unsigned short*)p; p += (size_t)512 * 512 * 2;      //    524,288
    unsigned short* z1_bf    = (unsigned short*)p; p += (size_t)512 * 1024 * 2;     //  1,048,576
    float* partial = (float*)p; p += (size_t)KSPLIT * B_SZ * LC_SZ * 4;             // 13,107,200
    float* attn_w  = (float*)p; p += (size_t)B_SZ * LC_SZ * 4;                      //    204,800
    float* gi      = (float*)p; p += (size_t)512 * 1536 * 4;                        //  3,145,728
    float* gh      = (float*)p; p += (size_t)512 * 1536 * 4;                        //  3,145,728
    float* lo      = (float*)p; p += (size_t)512 * O_SZ * 4;                        //  4,104,192
    float* z2      = (float*)p; p += (size_t)512 * 512 * 4;                         //  1,048,576
    float* z_t     = (float*)p; p += (size_t)512 * 4;                               // total ~107 MB

    float* out = (float*)d_out;

    cvt_weights<<<6082, 256, 0, stream>>>(attn_W, W_ih, W_hh, mlp_W, out_W, zt_W1, zt_W2,
                                          attnW_bf, Wih_bf, Whh_bf, mlpW_bf, outW_bf, ztW1_bf, ztW2_bf);
    embed_kernel<<<608, 256, 0, stream>>>(input, input_d, emb_w, emb_d_w, Abf, xm_bf);
    build_abf<<<26264, 256, 0, stream>>>(hidden, ans, annot, Abf, xm_bf);
    attn_gemm_bf<<<dim3(8, 2, KSPLIT), 256, 0, stream>>>(Abf, attnW_bf, partial);
    attn_softmax_ct<<<512, 256, 0, stream>>>(partial, attn_b, Abf, attn_w, xm_bf);
    // gh = h0 @ W_hh^T   (h0 lives as bf16 in Abf[:, 0:512], lda=AK)
    gemm_bf<<<dim3(8, 24), 256, 0, stream>>>(Abf, AK, Whh_bf, 512, b_hh, gh, nullptr, 1536, 1536, 512, 0);
    // gi = [c_t|ans|emb] @ W_ih^T
    gemm_bf<<<dim3(8, 24), 256, 0, stream>>>(xm_bf + 512, XK, Wih_bf, GIK, b_ih, gi, nullptr, 1536, 1536, GIK, 0);
    gru_kernel<<<1024, 256, 0, stream>>>(gi, gh, hidden, xm_bf, out);
    // e_t = xm @ mlp_W^T  (bf16 out only)
    gemm_bf<<<dim3(8, 8), 256, 0, stream>>>(xm_bf, XK, mlpW_bf, XK, mlp_b, nullptr, et_bf, 512, 512, XK, 0);
    // z1 = tanh(xm @ zt_W1^T)
    gemm_bf<<<dim3(8, 16), 256, 0, stream>>>(xm_bf, XK, ztW1_bf, XK, zt_b1, nullptr, z1_bf, 1024, 1024, XK, 1);
    // z2 = tanh(z1 @ zt_W2^T)
    gemm_bf<<<dim3(8, 8), 256, 0, stream>>>(z1_bf, 1024, ztW2_bf, 1024, zt_b2, z2, nullptr, 512, 512, 1024, 1);
    zt_kernel<<<512, 64, 0, stream>>>(z2, zt_W3, zt_b3, z_t);
    // lo = e_t @ out_W^T
    gemm_bf<<<dim3(8, 32), 256, 0, stream>>>(et_bf, 512, outW_bf, 512, out_b, lo, nullptr, O_SZ, O_SZ, 512, 0);
    out_softmax<<<512, 256, 0, stream>>>(lo, attn_w, z_t, out + 2 * B_SZ * H_SZ);
}